// Round 1
// baseline (3371.679 us; speedup 1.0000x reference)
//
#include <hip/hip_runtime.h>
#include <hip/hip_bf16.h>
#include <stdint.h>

// Problem constants
#define Bb 16
#define Ss 2048
#define Dd 1024
#define Hh 1024
#define Rr 16
#define Mm 32768   // B*S

typedef __attribute__((ext_vector_type(4))) float f32x4;
typedef __attribute__((ext_vector_type(8))) short bf16x8;

// RNE fp32 -> bf16 (inputs are finite; no NaN path needed)
__device__ __forceinline__ unsigned short f2bf(float f) {
    union { float f; uint32_t u; } c; c.f = f;
    uint32_t u = c.u + 0x7fffu + ((c.u >> 16) & 1u);
    return (unsigned short)(u >> 16);
}

// async global->LDS, 16B per lane. LDS dest = uniform base + lane*16.
__device__ __forceinline__ void gld16(const void* gsrc, void* ldst) {
    __builtin_amdgcn_global_load_lds(
        (const __attribute__((address_space(1))) unsigned int*)gsrc,
        (__attribute__((address_space(3))) unsigned int*)ldst, 16, 0, 0);
}

// ---------------------------------------------------------------------------
// Kernel 1: convert x, Wa, Wu to bf16 (flat, 4 elems/thread)
// ---------------------------------------------------------------------------
__global__ __launch_bounds__(256) void k_convert(
    const float* __restrict__ x, const float* __restrict__ Wa,
    const float* __restrict__ Wu,
    unsigned short* __restrict__ xb, unsigned short* __restrict__ Wab,
    unsigned short* __restrict__ Wub)
{
    long e = ((long)blockIdx.x * 256 + threadIdx.x) * 4;
    const long nx = (long)Mm * Dd;        // 33,554,432
    const long nw = (long)Hh * Dd;        // 1,048,576
    const float* src; unsigned short* dst; long o;
    if (e < nx)            { src = x;  dst = xb;  o = e; }
    else if (e < nx + nw)  { src = Wa; dst = Wab; o = e - nx; }
    else                   { src = Wu; dst = Wub; o = e - nx - nw; }
    float4 f = *(const float4*)(src + o);
    ushort4 r;
    r.x = f2bf(f.x); r.y = f2bf(f.y); r.z = f2bf(f.z); r.w = f2bf(f.w);
    *(ushort4*)(dst + o) = r;
}

// ---------------------------------------------------------------------------
// Kernel 2: C[M,1024] = Xb @ W^T (+bias, optional sigmoid), bf16 MFMA.
// grid = (256 m-tiles, 16 n-tiles); bn<8 -> a=sigmoid(..+ba); bn>=8 -> u_in
// 128x128 tile, BK=32, 4 waves (2x2), 4x4 16x16x32 accs per wave.
// ---------------------------------------------------------------------------
__global__ __launch_bounds__(256) void k_gemm(
    const unsigned short* __restrict__ Xb,   // [M, D] bf16 bits
    const unsigned short* __restrict__ Wab,  // [H, D]
    const unsigned short* __restrict__ Wub,  // [H, D]
    const float* __restrict__ ba, const float* __restrict__ bu,
    float* __restrict__ outA, float* __restrict__ outU)
{
    __shared__ short At[128 * 32];
    __shared__ short Bt[128 * 32];

    const int tid  = threadIdx.x;
    const int lane = tid & 63;
    const int wave = tid >> 6;
    const int bm = blockIdx.x;
    const int bn = blockIdx.y;
    const int region = bn >> 3;            // 0: a, 1: u_in
    const int nbase = (bn & 7) * 128;

    const short* Ag = (const short*)Xb;
    const short* Bg = (const short*)(region ? Wub : Wab);
    const float* bias = region ? bu : ba;
    float* outp = region ? outU : outA;

    const int wm = wave & 1, wn = wave >> 1;
    const int srow = lane >> 2, sseg = lane & 3;   // staging: 4 lanes/row
    const int mrow = lane & 15, kb = lane >> 4;    // fragment lane mapping

    f32x4 acc[4][4] = {};

    for (int kt = 0; kt < 32; ++kt) {
        __syncthreads();
        const int k0 = kt * 32;
        #pragma unroll
        for (int p = 0; p < 2; ++p) {
            const int row = p * 64 + wave * 16 + srow;
            const short* ga = Ag + (long)(bm * 128 + row) * Dd + k0 + sseg * 8;
            gld16((const void*)ga, (void*)&At[p * 2048 + wave * 512]);
            const short* gb = Bg + (long)(nbase + row) * Dd + k0 + sseg * 8;
            gld16((const void*)gb, (void*)&Bt[p * 2048 + wave * 512]);
        }
        __syncthreads();

        bf16x8 af[4], bq[4];
        #pragma unroll
        for (int i = 0; i < 4; ++i) {
            af[i] = *(const bf16x8*)&At[(wm * 64 + i * 16 + mrow) * 32 + kb * 8];
            bq[i] = *(const bf16x8*)&Bt[(wn * 64 + i * 16 + mrow) * 32 + kb * 8];
        }
        #pragma unroll
        for (int i = 0; i < 4; ++i)
            #pragma unroll
            for (int j = 0; j < 4; ++j)
                acc[i][j] = __builtin_amdgcn_mfma_f32_16x16x32_bf16(
                    af[i], bq[j], acc[i][j], 0, 0, 0);
    }

    // Epilogue: C/D layout col=lane&15, row=(lane>>4)*4+reg (m89-verified)
    const int col = lane & 15, rq = lane >> 4;
    #pragma unroll
    for (int j = 0; j < 4; ++j) {
        const int n = nbase + wn * 64 + j * 16 + col;
        const float bv = bias[n];
        #pragma unroll
        for (int i = 0; i < 4; ++i) {
            const int mb = bm * 128 + wm * 64 + i * 16 + rq * 4;
            #pragma unroll
            for (int r = 0; r < 4; ++r) {
                float vv = acc[i][j][r] + bv;
                if (region == 0) vv = 1.0f / (1.0f + __expf(-vv));
                outp[(long)(mb + r) * Hh + n] = vv;
            }
        }
    }
}

// ---------------------------------------------------------------------------
// Kernel 3: g[M,16] = x @ Wg^T + bg (fp32, tiny N)
// block = 256 threads = 16 m-rows x 16 r
// ---------------------------------------------------------------------------
__global__ __launch_bounds__(256) void k_g(
    const float* __restrict__ x, const float* __restrict__ Wg,
    const float* __restrict__ bg, float* __restrict__ g)
{
    const int tid = threadIdx.x;
    const int r = tid & 15, ml = tid >> 4;
    const long m = (long)blockIdx.x * 16 + ml;
    const float4* xr = (const float4*)(x + m * Dd);
    const float4* wr = (const float4*)(Wg + (long)r * Dd);
    float acc = 0.0f;
    #pragma unroll 4
    for (int k = 0; k < Dd / 4; ++k) {
        float4 a = xr[k], b = wr[k];
        acc = fmaf(a.x, b.x, acc); acc = fmaf(a.y, b.y, acc);
        acc = fmaf(a.z, b.z, acc); acc = fmaf(a.w, b.w, acc);
    }
    g[m * Rr + r] = acc + bg[r];
}

// ---------------------------------------------------------------------------
// Kernel 4: sequential scan. One block per b (16 blocks x 1024 threads).
// Per step: r[16] = V^T s (wave w owns r=w, reads s from padded LDS),
//           q = g_t * r, s = a_t*s + u_t + U q.
// ---------------------------------------------------------------------------
__global__ __launch_bounds__(1024) void k_scan(
    const float* __restrict__ a,    // [B,S,H]
    const float* __restrict__ uin,  // [B,S,H]
    const float* __restrict__ g,    // [B,S,R]
    const float* __restrict__ u,    // [H,R]
    const float* __restrict__ v,    // [H,R]
    float* __restrict__ out)        // [B,H]
{
    // s[h] stored at sbuf[20*(h>>4) + (h&15)]; stride 20 dwords kills the
    // 64B-stride bank pathology and keeps 16B alignment for b128 reads.
    __shared__ __align__(16) float sbuf[64 * 20];
    __shared__ __align__(16) float qbuf[16];

    const int tid = threadIdx.x;
    const int lane = tid & 63, wave = tid >> 6;
    const int b = blockIdx.x;

    // u row for this h (update phase): u[h][0..15]
    float ur[16];
    #pragma unroll
    for (int r4 = 0; r4 < 4; ++r4) {
        float4 t4 = *(const float4*)&u[tid * Rr + r4 * 4];
        ur[r4 * 4 + 0] = t4.x; ur[r4 * 4 + 1] = t4.y;
        ur[r4 * 4 + 2] = t4.z; ur[r4 * 4 + 3] = t4.w;
    }
    // v column slice for reduction phase: lane i covers h=16i..16i+15, r=wave
    float vr[16];
    #pragma unroll
    for (int j = 0; j < 16; ++j) vr[j] = v[(lane * 16 + j) * Rr + wave];

    const float* ap = a   + (long)b * Ss * Hh + tid;
    const float* up = uin + (long)b * Ss * Hh + tid;
    const float* gp = g   + (long)b * Ss * Rr + wave;

    float s = 0.0f;
    float pa[4], pu[4], pg[4];
    #pragma unroll
    for (int t = 0; t < 4; ++t) { pa[t] = ap[t * Hh]; pu[t] = up[t * Hh]; }
    if (lane == 0) {
        #pragma unroll
        for (int t = 0; t < 4; ++t) pg[t] = gp[t * Rr];
    }
    ap += 4 * Hh; up += 4 * Hh; gp += 4 * Rr;

    const int sidx = 20 * (tid >> 4) + (tid & 15);
    sbuf[sidx] = s;
    __syncthreads();

    for (int t = 0; t < Ss; ++t) {
        const int ring = t & 3;
        // --- phase 1: r_wave = sum_h s[h] * v[h][wave] ---
        float part = 0.0f;
        const float* sp = &sbuf[20 * lane];
        #pragma unroll
        for (int q4 = 0; q4 < 4; ++q4) {
            float4 sv = *(const float4*)(sp + q4 * 4);
            part = fmaf(sv.x, vr[q4 * 4 + 0], part);
            part = fmaf(sv.y, vr[q4 * 4 + 1], part);
            part = fmaf(sv.z, vr[q4 * 4 + 2], part);
            part = fmaf(sv.w, vr[q4 * 4 + 3], part);
        }
        #pragma unroll
        for (int m = 1; m < 64; m <<= 1) part += __shfl_xor(part, m);
        if (lane == 0) qbuf[wave] = pg[ring] * part;
        __syncthreads();

        // --- phase 2: s = a*s + u + sum_r q[r]*u[h][r] ---
        float4 q0 = *(const float4*)&qbuf[0];
        float4 q1 = *(const float4*)&qbuf[4];
        float4 q2 = *(const float4*)&qbuf[8];
        float4 q3 = *(const float4*)&qbuf[12];
        float lr = 0.0f;
        lr = fmaf(q0.x, ur[0],  lr); lr = fmaf(q0.y, ur[1],  lr);
        lr = fmaf(q0.z, ur[2],  lr); lr = fmaf(q0.w, ur[3],  lr);
        lr = fmaf(q1.x, ur[4],  lr); lr = fmaf(q1.y, ur[5],  lr);
        lr = fmaf(q1.z, ur[6],  lr); lr = fmaf(q1.w, ur[7],  lr);
        lr = fmaf(q2.x, ur[8],  lr); lr = fmaf(q2.y, ur[9],  lr);
        lr = fmaf(q2.z, ur[10], lr); lr = fmaf(q2.w, ur[11], lr);
        lr = fmaf(q3.x, ur[12], lr); lr = fmaf(q3.y, ur[13], lr);
        lr = fmaf(q3.z, ur[14], lr); lr = fmaf(q3.w, ur[15], lr);
        s = fmaf(pa[ring], s, pu[ring] + lr);
        sbuf[sidx] = s;

        // --- prefetch t+4 ---
        if (t < Ss - 4) {
            pa[ring] = ap[0]; pu[ring] = up[0];
            ap += Hh; up += Hh;
            if (lane == 0) { pg[ring] = gp[0]; gp += Rr; }
        }
        __syncthreads();
    }
    out[(long)b * Hh + tid] = s;
}

// ---------------------------------------------------------------------------
extern "C" void kernel_launch(void* const* d_in, const int* in_sizes, int n_in,
                              void* d_out, int out_size, void* d_ws, size_t ws_size,
                              hipStream_t stream)
{
    const float* x  = (const float*)d_in[0];
    const float* Wa = (const float*)d_in[1];
    const float* ba = (const float*)d_in[2];
    const float* Wg = (const float*)d_in[3];
    const float* bg = (const float*)d_in[4];
    const float* Wu = (const float*)d_in[5];
    const float* bu = (const float*)d_in[6];
    const float* u  = (const float*)d_in[7];
    const float* v  = (const float*)d_in[8];
    float* out = (float*)d_out;

    char* ws = (char*)d_ws;
    unsigned short* xb   = (unsigned short*)(ws);                // 67,108,864 B
    unsigned short* Wab  = (unsigned short*)(ws + 67108864);     //  2,097,152 B
    unsigned short* Wub  = (unsigned short*)(ws + 69206016);     //  2,097,152 B
    float*          abuf = (float*)(ws + 71303168);              // 134,217,728 B
    float*          ubuf = (float*)(ws + 205520896);             // 134,217,728 B
    float*          gbuf = (float*)(ws + 339738624);             //  2,097,152 B

    hipLaunchKernelGGL(k_convert, dim3(34816), dim3(256), 0, stream,
                       x, Wa, Wu, xb, Wab, Wub);
    hipLaunchKernelGGL(k_gemm, dim3(256, 16), dim3(256), 0, stream,
                       xb, Wab, Wub, ba, bu, abuf, ubuf);
    hipLaunchKernelGGL(k_g, dim3(2048), dim3(256), 0, stream,
                       x, Wg, bg, gbuf);
    hipLaunchKernelGGL(k_scan, dim3(Bb), dim3(1024), 0, stream,
                       abuf, ubuf, gbuf, u, v, out);
}

// Round 2
// 2087.068 us; speedup vs baseline: 1.6155x; 1.6155x over previous
//
#include <hip/hip_runtime.h>
#include <hip/hip_bf16.h>
#include <stdint.h>

// Problem constants
#define Bb 16
#define Ss 2048
#define Dd 1024
#define Hh 1024
#define Rr 16
#define Mm 32768   // B*S

typedef __attribute__((ext_vector_type(4))) float f32x4;
typedef __attribute__((ext_vector_type(2))) float f32x2;
typedef __attribute__((ext_vector_type(8))) short bf16x8;

// RNE fp32 -> bf16 (inputs are finite; no NaN path needed)
__device__ __forceinline__ unsigned short f2bf(float f) {
    union { float f; uint32_t u; } c; c.f = f;
    uint32_t u = c.u + 0x7fffu + ((c.u >> 16) & 1u);
    return (unsigned short)(u >> 16);
}

// async global->LDS, 16B per lane. LDS dest = uniform base + lane*16.
__device__ __forceinline__ void gld16(const void* gsrc, void* ldst) {
    __builtin_amdgcn_global_load_lds(
        (const __attribute__((address_space(1))) unsigned int*)gsrc,
        (__attribute__((address_space(3))) unsigned int*)ldst, 16, 0, 0);
}

// Raw workgroup barrier WITHOUT the vmcnt(0) drain __syncthreads carries.
// lgkmcnt(0) makes LDS writes visible across waves; outstanding global
// (prefetch) loads stay in flight. asm clobbers pin compiler ordering.
// imm 0xC07F = vmcnt(63) expcnt(7) lgkmcnt(0)  [gfx9 encoding]
__device__ __forceinline__ void softbar() {
    __asm volatile("" ::: "memory");
    __builtin_amdgcn_s_waitcnt(0xC07F);
    __builtin_amdgcn_s_barrier();
    __asm volatile("" ::: "memory");
}

// ---------------------------------------------------------------------------
// Kernel 1: convert x, Wa, Wu to bf16 (flat, 4 elems/thread)
// ---------------------------------------------------------------------------
__global__ __launch_bounds__(256) void k_convert(
    const float* __restrict__ x, const float* __restrict__ Wa,
    const float* __restrict__ Wu,
    unsigned short* __restrict__ xb, unsigned short* __restrict__ Wab,
    unsigned short* __restrict__ Wub)
{
    long e = ((long)blockIdx.x * 256 + threadIdx.x) * 4;
    const long nx = (long)Mm * Dd;        // 33,554,432
    const long nw = (long)Hh * Dd;        // 1,048,576
    const float* src; unsigned short* dst; long o;
    if (e < nx)            { src = x;  dst = xb;  o = e; }
    else if (e < nx + nw)  { src = Wa; dst = Wab; o = e - nx; }
    else                   { src = Wu; dst = Wub; o = e - nx - nw; }
    float4 f = *(const float4*)(src + o);
    ushort4 r;
    r.x = f2bf(f.x); r.y = f2bf(f.y); r.z = f2bf(f.z); r.w = f2bf(f.w);
    *(ushort4*)(dst + o) = r;
}

// ---------------------------------------------------------------------------
// Kernel 2: C[M,1024] = Xb @ W^T (+bias, optional sigmoid), bf16 MFMA.
// grid = (256 m-tiles, 16 n-tiles); bn<8 -> a=sigmoid(..+ba); bn>=8 -> u_in
// 128x128 tile, BK=32, 4 waves (2x2), 4x4 16x16x32 accs per wave.
// ---------------------------------------------------------------------------
__global__ __launch_bounds__(256) void k_gemm(
    const unsigned short* __restrict__ Xb,   // [M, D] bf16 bits
    const unsigned short* __restrict__ Wab,  // [H, D]
    const unsigned short* __restrict__ Wub,  // [H, D]
    const float* __restrict__ ba, const float* __restrict__ bu,
    float* __restrict__ outA, float* __restrict__ outU)
{
    __shared__ short At[128 * 32];
    __shared__ short Bt[128 * 32];

    const int tid  = threadIdx.x;
    const int lane = tid & 63;
    const int wave = tid >> 6;
    const int bm = blockIdx.x;
    const int bn = blockIdx.y;
    const int region = bn >> 3;            // 0: a, 1: u_in
    const int nbase = (bn & 7) * 128;

    const short* Ag = (const short*)Xb;
    const short* Bg = (const short*)(region ? Wub : Wab);
    const float* bias = region ? bu : ba;
    float* outp = region ? outU : outA;

    const int wm = wave & 1, wn = wave >> 1;
    const int srow = lane >> 2, sseg = lane & 3;   // staging: 4 lanes/row
    const int mrow = lane & 15, kb = lane >> 4;    // fragment lane mapping

    f32x4 acc[4][4] = {};

    for (int kt = 0; kt < 32; ++kt) {
        __syncthreads();
        const int k0 = kt * 32;
        #pragma unroll
        for (int p = 0; p < 2; ++p) {
            const int row = p * 64 + wave * 16 + srow;
            const short* ga = Ag + (long)(bm * 128 + row) * Dd + k0 + sseg * 8;
            gld16((const void*)ga, (void*)&At[p * 2048 + wave * 512]);
            const short* gb = Bg + (long)(nbase + row) * Dd + k0 + sseg * 8;
            gld16((const void*)gb, (void*)&Bt[p * 2048 + wave * 512]);
        }
        __syncthreads();

        bf16x8 af[4], bq[4];
        #pragma unroll
        for (int i = 0; i < 4; ++i) {
            af[i] = *(const bf16x8*)&At[(wm * 64 + i * 16 + mrow) * 32 + kb * 8];
            bq[i] = *(const bf16x8*)&Bt[(wn * 64 + i * 16 + mrow) * 32 + kb * 8];
        }
        #pragma unroll
        for (int i = 0; i < 4; ++i)
            #pragma unroll
            for (int j = 0; j < 4; ++j)
                acc[i][j] = __builtin_amdgcn_mfma_f32_16x16x32_bf16(
                    af[i], bq[j], acc[i][j], 0, 0, 0);
    }

    // Epilogue: C/D layout col=lane&15, row=(lane>>4)*4+reg (m89-verified)
    const int col = lane & 15, rq = lane >> 4;
    #pragma unroll
    for (int j = 0; j < 4; ++j) {
        const int n = nbase + wn * 64 + j * 16 + col;
        const float bv = bias[n];
        #pragma unroll
        for (int i = 0; i < 4; ++i) {
            const int mb = bm * 128 + wm * 64 + i * 16 + rq * 4;
            #pragma unroll
            for (int r = 0; r < 4; ++r) {
                float vv = acc[i][j][r] + bv;
                if (region == 0) vv = 1.0f / (1.0f + __expf(-vv));
                outp[(long)(mb + r) * Hh + n] = vv;
            }
        }
    }
}

// ---------------------------------------------------------------------------
// Kernel 3: g[M,16] = x @ Wg^T + bg (fp32, tiny N)
// block = 256 threads = 16 m-rows x 16 r
// ---------------------------------------------------------------------------
__global__ __launch_bounds__(256) void k_g(
    const float* __restrict__ x, const float* __restrict__ Wg,
    const float* __restrict__ bg, float* __restrict__ g)
{
    const int tid = threadIdx.x;
    const int r = tid & 15, ml = tid >> 4;
    const long m = (long)blockIdx.x * 16 + ml;
    const float4* xr = (const float4*)(x + m * Dd);
    const float4* wr = (const float4*)(Wg + (long)r * Dd);
    float acc = 0.0f;
    #pragma unroll 4
    for (int k = 0; k < Dd / 4; ++k) {
        float4 a = xr[k], b = wr[k];
        acc = fmaf(a.x, b.x, acc); acc = fmaf(a.y, b.y, acc);
        acc = fmaf(a.z, b.z, acc); acc = fmaf(a.w, b.w, acc);
    }
    g[m * Rr + r] = acc + bg[r];
}

// ---------------------------------------------------------------------------
// Kernel 4: sequential scan. One block per b (16 blocks x 1024 threads).
// Per step: r[16] = V^T s (wave w owns r=w, reads s from padded LDS),
//           q = g_t * r, s = a_t*s + u_t + U q.
// Raw barriers (softbar) keep the 4-step global prefetch ring IN FLIGHT
// across step boundaries — __syncthreads would drain vmcnt every step
// and expose full HBM latency (R1 showed 3130 cyc/step from exactly that).
// ---------------------------------------------------------------------------
__global__ __launch_bounds__(1024) void k_scan(
    const float* __restrict__ a,    // [B,S,H]
    const float* __restrict__ uin,  // [B,S,H]
    const float* __restrict__ g,    // [B,S,R]
    const float* __restrict__ u,    // [H,R]
    const float* __restrict__ v,    // [H,R]
    float* __restrict__ out)        // [B,H]
{
    // s[h] at sbuf[20*(h>>4) + (h&15)]: 80B row stride keeps 16B alignment
    // for b128 reads; 8-way bank aliasing on the strided read is ~3x on 4
    // instrs — negligible vs the step's latency chain.
    __shared__ __align__(16) float sbuf[64 * 20];
    __shared__ __align__(16) float qbuf[16];

    const int tid = threadIdx.x;
    const int lane = tid & 63, wave = tid >> 6;
    const int b = blockIdx.x;

    // u row for this h (update phase): u[h][0..15], as 8 packed pairs
    f32x2 ur2[8];
    #pragma unroll
    for (int r4 = 0; r4 < 8; ++r4)
        ur2[r4] = *(const f32x2*)&u[tid * Rr + r4 * 2];
    // v column slice (reduction phase): lane i covers h=16i..16i+15, r=wave
    f32x2 vr2[8];
    #pragma unroll
    for (int j = 0; j < 8; ++j) {
        f32x2 t;
        t.x = v[(lane * 16 + j * 2 + 0) * Rr + wave];
        t.y = v[(lane * 16 + j * 2 + 1) * Rr + wave];
        vr2[j] = t;
    }

    const float* ap = a   + (long)b * Ss * Hh + tid;
    const float* up = uin + (long)b * Ss * Hh + tid;
    const float* gp = g   + (long)b * Ss * Rr + wave;   // same addr all lanes of wave

    float s = 0.0f;
    float pa[4], pu[4], pg[4];
    #pragma unroll
    for (int t = 0; t < 4; ++t) {
        pa[t] = ap[t * Hh]; pu[t] = up[t * Hh]; pg[t] = gp[t * Rr];
    }
    ap += 4 * Hh; up += 4 * Hh; gp += 4 * Rr;

    const int sidx = 20 * (tid >> 4) + (tid & 15);
    const float* sp = &sbuf[20 * lane];
    sbuf[sidx] = s;
    softbar();

#define STEP(R, PF) do {                                                    \
    f32x4 sA = *(const f32x4*)(sp);                                         \
    f32x4 sB = *(const f32x4*)(sp + 4);                                     \
    f32x4 sC = *(const f32x4*)(sp + 8);                                     \
    f32x4 sD = *(const f32x4*)(sp + 12);                                    \
    f32x2 pk = sA.xy * vr2[0];                                              \
    pk += sA.zw * vr2[1];                                                   \
    pk += sB.xy * vr2[2];                                                   \
    pk += sB.zw * vr2[3];                                                   \
    pk += sC.xy * vr2[4];                                                   \
    pk += sC.zw * vr2[5];                                                   \
    pk += sD.xy * vr2[6];                                                   \
    pk += sD.zw * vr2[7];                                                   \
    float part = pk.x + pk.y;                                               \
    part += __shfl_xor(part, 1);                                            \
    part += __shfl_xor(part, 2);                                            \
    part += __shfl_xor(part, 4);                                            \
    part += __shfl_xor(part, 8);                                            \
    part += __shfl_xor(part, 16);                                           \
    part += __shfl_xor(part, 32);                                           \
    if (lane == 0) qbuf[wave] = pg[R] * part;                               \
    softbar();                                                              \
    f32x4 qA = *(const f32x4*)(qbuf);                                       \
    f32x4 qB = *(const f32x4*)(qbuf + 4);                                   \
    f32x4 qC = *(const f32x4*)(qbuf + 8);                                   \
    f32x4 qD = *(const f32x4*)(qbuf + 12);                                  \
    f32x2 lk = qA.xy * ur2[0];                                              \
    lk += qA.zw * ur2[1];                                                   \
    lk += qB.xy * ur2[2];                                                   \
    lk += qB.zw * ur2[3];                                                   \
    lk += qC.xy * ur2[4];                                                   \
    lk += qC.zw * ur2[5];                                                   \
    lk += qD.xy * ur2[6];                                                   \
    lk += qD.zw * ur2[7];                                                   \
    s = fmaf(pa[R], s, pu[R] + (lk.x + lk.y));                              \
    sbuf[sidx] = s;                                                         \
    if (PF) {                                                               \
        pa[R] = *ap; ap += Hh;                                              \
        pu[R] = *up; up += Hh;                                              \
        pg[R] = *gp; gp += Rr;                                              \
    }                                                                       \
    softbar();                                                              \
} while (0)

    for (int t4 = 0; t4 < Ss / 4 - 1; ++t4) {
        STEP(0, 1); STEP(1, 1); STEP(2, 1); STEP(3, 1);
    }
    STEP(0, 0); STEP(1, 0); STEP(2, 0); STEP(3, 0);
#undef STEP

    out[(long)b * Hh + tid] = s;
}

// ---------------------------------------------------------------------------
extern "C" void kernel_launch(void* const* d_in, const int* in_sizes, int n_in,
                              void* d_out, int out_size, void* d_ws, size_t ws_size,
                              hipStream_t stream)
{
    const float* x  = (const float*)d_in[0];
    const float* Wa = (const float*)d_in[1];
    const float* ba = (const float*)d_in[2];
    const float* Wg = (const float*)d_in[3];
    const float* bg = (const float*)d_in[4];
    const float* Wu = (const float*)d_in[5];
    const float* bu = (const float*)d_in[6];
    const float* u  = (const float*)d_in[7];
    const float* v  = (const float*)d_in[8];
    float* out = (float*)d_out;

    char* ws = (char*)d_ws;
    unsigned short* xb   = (unsigned short*)(ws);                // 67,108,864 B
    unsigned short* Wab  = (unsigned short*)(ws + 67108864);     //  2,097,152 B
    unsigned short* Wub  = (unsigned short*)(ws + 69206016);     //  2,097,152 B
    float*          abuf = (float*)(ws + 71303168);              // 134,217,728 B
    float*          ubuf = (float*)(ws + 205520896);             // 134,217,728 B
    float*          gbuf = (float*)(ws + 339738624);             //  2,097,152 B

    hipLaunchKernelGGL(k_convert, dim3(34816), dim3(256), 0, stream,
                       x, Wa, Wu, xb, Wab, Wub);
    hipLaunchKernelGGL(k_gemm, dim3(256, 16), dim3(256), 0, stream,
                       xb, Wab, Wub, ba, bu, abuf, ubuf);
    hipLaunchKernelGGL(k_g, dim3(2048), dim3(256), 0, stream,
                       x, Wg, bg, gbuf);
    hipLaunchKernelGGL(k_scan, dim3(Bb), dim3(1024), 0, stream,
                       abuf, ubuf, gbuf, u, v, out);
}